// Round 4
// baseline (287.211 us; speedup 1.0000x reference)
//
#include <hip/hip_runtime.h>
#include <stdint.h>

// FrequencySemanticCipher: enc = image + idwt(noise/maxabs), then per-batch min-max norm.
// PRNG: JAX threefry2x32, partitionable semantics (verified R2: absmax 3.9e-3).
//
// R2 lesson: device-scope atomics serialize ~11ns per ADDRESS at memory fabric.
//   => stripe atomic targets across padded 64B lines, few-hundred atomics/address max.
// R3 lesson: k_enc was VALU-bound (85% VALUBusy, 20% HBM) on duplicated threefry.
//   => K1 stores folded bits into d_out at the very positions k_enc later rewrites
//      (same-thread read-then-write => in-place safe), k_enc drops its threefry.

#define CHW4 196608        // 3*512*512/4 (float4 per batch)

// ws layout (uint32 words); atomic targets each own a 64B line:
#define WS_SCALE 8          // [8..11] float 1/(maxabs+eps) per subband
#define STRMAX  16          // + (s*64+stripe)*16, s<4, stripe<64   (init 0)
#define STRMIN  4112        // + (s*64+stripe)*16                    (init 0xFFFFFFFF)
#define BMN     8208        // + b*16, b<32  mapped batch min        (init 0xFFFFFFFF)
#define BMX     8720        // + b*16        mapped batch max        (init 0)

struct U2 { uint32_t x, y; };

__device__ __forceinline__ U2 threefry(uint32_t k0, uint32_t k1, uint32_t x0, uint32_t x1) {
  uint32_t ks2 = k0 ^ k1 ^ 0x1BD11BDAu;
  x0 += k0; x1 += k1;
#define TF_R(r) { x0 += x1; x1 = (x1 << (r)) | (x1 >> (32 - (r))); x1 ^= x0; }
  TF_R(13) TF_R(15) TF_R(26) TF_R(6)
  x0 += k1; x1 += ks2 + 1u;
  TF_R(17) TF_R(29) TF_R(16) TF_R(24)
  x0 += ks2; x1 += k0 + 2u;
  TF_R(13) TF_R(15) TF_R(26) TF_R(6)
  x0 += k0; x1 += k1 + 3u;
  TF_R(17) TF_R(29) TF_R(16) TF_R(24)
  x0 += k1; x1 += ks2 + 4u;
  TF_R(13) TF_R(15) TF_R(26) TF_R(6)
  x0 += ks2; x1 += k0 + 5u;
#undef TF_R
  U2 r; r.x = x0; r.y = x1; return r;
}

__device__ __forceinline__ uint32_t threefry_fold(uint32_t k0, uint32_t k1, uint32_t x1) {
  U2 r = threefry(k0, k1, 0u, x1);
  return r.x ^ r.y;
}

// XLA ErfInv32 (Giles) polynomial
__device__ __forceinline__ float erfinv_f32(float x) {
  float w = -logf(1.0f - x * x);
  float p;
  if (w < 5.0f) {
    w = w - 2.5f;
    p = 2.81022636e-08f;
    p = fmaf(p, w, 3.43273939e-07f);
    p = fmaf(p, w, -3.5233877e-06f);
    p = fmaf(p, w, -4.39150654e-06f);
    p = fmaf(p, w, 0.00021858087f);
    p = fmaf(p, w, -0.00125372503f);
    p = fmaf(p, w, -0.00417768164f);
    p = fmaf(p, w, 0.246640727f);
    p = fmaf(p, w, 1.50140941f);
  } else {
    w = sqrtf(w) - 3.0f;
    p = -0.000200214257f;
    p = fmaf(p, w, 0.000100950558f);
    p = fmaf(p, w, 0.00134934322f);
    p = fmaf(p, w, -0.00367342844f);
    p = fmaf(p, w, 0.00573950773f);
    p = fmaf(p, w, -0.0076224613f);
    p = fmaf(p, w, 0.00943887047f);
    p = fmaf(p, w, 1.00167406f);
    p = fmaf(p, w, 2.83297682f);
  }
  return p * x;
}

__device__ __forceinline__ float normal_from_bits(uint32_t bits) {
  uint32_t fb = (bits >> 9) | 0x3f800000u;
  float f = __uint_as_float(fb) - 1.0f;      // [0,1)
  const float lo = -0.99999994f;
  float u = fmaxf(lo, f * 2.0f + lo);
  return 1.41421354f * erfinv_f32(u);
}

__device__ __forceinline__ uint32_t map_ord(float f) {
  uint32_t s = __float_as_uint(f);
  return (s & 0x80000000u) ? ~s : (s | 0x80000000u);
}
__device__ __forceinline__ float unmap_ord(uint32_t u) {
  return (u & 0x80000000u) ? __uint_as_float(u ^ 0x80000000u) : __uint_as_float(~u);
}

__global__ void k_init(uint32_t* ws) {
  int t = threadIdx.x;
  if (t == 0) {
    for (int i = 0; i < 4; ++i) {
      U2 r = threefry(0u, 123u, 0u, (uint32_t)i);
      ws[2 * i] = r.x;
      ws[2 * i + 1] = r.y;
    }
  }
  for (int i = t; i < 4096; i += 256) {
    ws[STRMAX + i] = 0u;
    ws[STRMIN + i] = 0xFFFFFFFFu;
  }
  for (int i = t; i < 512; i += 256) {
    ws[BMN + i] = 0xFFFFFFFFu;
    ws[BMX + i] = 0u;
  }
}

// K1: generate folded bits, store into d_out at final image positions,
// track per-subband bits min/max -> striped atomics.
__global__ __launch_bounds__(256) void k_bits(uint32_t* __restrict__ outb,
                                              uint32_t* __restrict__ ws) {
  const int j = threadIdx.x;       // 0..255
  const int i = blockIdx.x;        // 0..255
  const int c = blockIdx.y;        // 0..2
  const int b = blockIdx.z;        // 0..31
  const uint32_t idx = ((uint32_t)(b * 3 + c) << 16) | ((uint32_t)i << 8) | (uint32_t)j;
  uint32_t u0 = threefry_fold(ws[0], ws[1], idx);
  uint32_t u1 = threefry_fold(ws[2], ws[3], idx);
  uint32_t u2 = threefry_fold(ws[4], ws[5], idx);
  uint32_t u3 = threefry_fold(ws[6], ws[7], idx);
  size_t base = ((size_t)(b * 3 + c) * 512 + 2 * i) * 512 + 2 * j;
  *(uint2*)(outb + base)       = make_uint2(u0, u1);
  *(uint2*)(outb + base + 512) = make_uint2(u2, u3);
  uint32_t mx0 = u0, mx1 = u1, mx2 = u2, mx3 = u3;
  uint32_t mn0 = u0, mn1 = u1, mn2 = u2, mn3 = u3;
  #pragma unroll
  for (int off = 32; off > 0; off >>= 1) {
    mx0 = max(mx0, (uint32_t)__shfl_down(mx0, off));
    mx1 = max(mx1, (uint32_t)__shfl_down(mx1, off));
    mx2 = max(mx2, (uint32_t)__shfl_down(mx2, off));
    mx3 = max(mx3, (uint32_t)__shfl_down(mx3, off));
    mn0 = min(mn0, (uint32_t)__shfl_down(mn0, off));
    mn1 = min(mn1, (uint32_t)__shfl_down(mn1, off));
    mn2 = min(mn2, (uint32_t)__shfl_down(mn2, off));
    mn3 = min(mn3, (uint32_t)__shfl_down(mn3, off));
  }
  __shared__ uint32_t smx[4][4], smn[4][4];
  const int lane = threadIdx.x & 63, w = threadIdx.x >> 6;
  if (lane == 0) {
    smx[w][0] = mx0; smx[w][1] = mx1; smx[w][2] = mx2; smx[w][3] = mx3;
    smn[w][0] = mn0; smn[w][1] = mn1; smn[w][2] = mn2; smn[w][3] = mn3;
  }
  __syncthreads();
  const int stripe = (blockIdx.x + 256 * blockIdx.y + 768 * blockIdx.z) & 63;
  const int t = threadIdx.x;
  if (t < 4) {
    uint32_t m = max(max(smx[0][t], smx[1][t]), max(smx[2][t], smx[3][t]));
    atomicMax(&ws[STRMAX + (t * 64 + stripe) * 16], m);
  } else if (t < 8) {
    int s = t - 4;
    uint32_t m = min(min(smn[0][s], smn[1][s]), min(smn[2][s], smn[3][s]));
    atomicMin(&ws[STRMIN + (s * 64 + stripe) * 16], m);
  }
}

// K2: reduce stripes -> per-subband 1/(maxabs+eps)
__global__ void k_scales(uint32_t* ws) {
  const int t = threadIdx.x;   // 64 threads; stripe = t
  uint32_t mx0, mx1, mx2, mx3, mn0, mn1, mn2, mn3;
  mx0 = ws[STRMAX + (0 * 64 + t) * 16];
  mx1 = ws[STRMAX + (1 * 64 + t) * 16];
  mx2 = ws[STRMAX + (2 * 64 + t) * 16];
  mx3 = ws[STRMAX + (3 * 64 + t) * 16];
  mn0 = ws[STRMIN + (0 * 64 + t) * 16];
  mn1 = ws[STRMIN + (1 * 64 + t) * 16];
  mn2 = ws[STRMIN + (2 * 64 + t) * 16];
  mn3 = ws[STRMIN + (3 * 64 + t) * 16];
  #pragma unroll
  for (int off = 32; off > 0; off >>= 1) {
    mx0 = max(mx0, (uint32_t)__shfl_down(mx0, off));
    mx1 = max(mx1, (uint32_t)__shfl_down(mx1, off));
    mx2 = max(mx2, (uint32_t)__shfl_down(mx2, off));
    mx3 = max(mx3, (uint32_t)__shfl_down(mx3, off));
    mn0 = min(mn0, (uint32_t)__shfl_down(mn0, off));
    mn1 = min(mn1, (uint32_t)__shfl_down(mn1, off));
    mn2 = min(mn2, (uint32_t)__shfl_down(mn2, off));
    mn3 = min(mn3, (uint32_t)__shfl_down(mn3, off));
  }
  if (t == 0) {
    float* wsf = (float*)ws;
    wsf[WS_SCALE + 0] = 1.0f / (fmaxf(normal_from_bits(mx0), -normal_from_bits(mn0)) + 1e-8f);
    wsf[WS_SCALE + 1] = 1.0f / (fmaxf(normal_from_bits(mx1), -normal_from_bits(mn1)) + 1e-8f);
    wsf[WS_SCALE + 2] = 1.0f / (fmaxf(normal_from_bits(mx2), -normal_from_bits(mn2)) + 1e-8f);
    wsf[WS_SCALE + 3] = 1.0f / (fmaxf(normal_from_bits(mx3), -normal_from_bits(mn3)) + 1e-8f);
  }
}

// K3: enc = image + idwt(scaled noise) from stored bits (in-place in d_out);
// per-batch min/max -> per-batch padded atomics.
__global__ __launch_bounds__(256) void k_enc(const float* __restrict__ img,
                                             float* __restrict__ out,
                                             uint32_t* __restrict__ ws) {
  const int j = threadIdx.x;
  const int i = blockIdx.x;
  const int c = blockIdx.y;
  const int b = blockIdx.z;
  size_t base = ((size_t)(b * 3 + c) * 512 + 2 * i) * 512 + 2 * j;
  const uint2 bu0 = *(const uint2*)((const uint32_t*)out + base);
  const uint2 bu1 = *(const uint2*)((const uint32_t*)out + base + 512);
  const float2 r0 = *(const float2*)(img + base);
  const float2 r1 = *(const float2*)(img + base + 512);
  const float* wsf = (const float*)ws;
  float n0 = normal_from_bits(bu0.x) * wsf[WS_SCALE + 0];
  float n1 = normal_from_bits(bu0.y) * wsf[WS_SCALE + 1];
  float n2 = normal_from_bits(bu1.x) * wsf[WS_SCALE + 2];
  float n3 = normal_from_bits(bu1.y) * wsf[WS_SCALE + 3];
  float qa = 0.5f * (n0 + n1 + n2 + n3);
  float qb = 0.5f * (n0 + n1 - n2 - n3);
  float qc = 0.5f * (n0 - n1 + n2 - n3);
  float qd = 0.5f * (n0 - n1 - n2 + n3);
  float e00 = r0.x + qa, e01 = r0.y + qb, e10 = r1.x + qc, e11 = r1.y + qd;
  *(float2*)(out + base) = make_float2(e00, e01);
  *(float2*)(out + base + 512) = make_float2(e10, e11);
  float vmin = fminf(fminf(e00, e01), fminf(e10, e11));
  float vmax = fmaxf(fmaxf(e00, e01), fmaxf(e10, e11));
  #pragma unroll
  for (int off = 32; off > 0; off >>= 1) {
    vmin = fminf(vmin, __shfl_down(vmin, off));
    vmax = fmaxf(vmax, __shfl_down(vmax, off));
  }
  __shared__ float smin[4], smax[4];
  const int lane = threadIdx.x & 63, w = threadIdx.x >> 6;
  if (lane == 0) { smin[w] = vmin; smax[w] = vmax; }
  __syncthreads();
  if (threadIdx.x == 0) {
    vmin = fminf(fminf(smin[0], smin[1]), fminf(smin[2], smin[3]));
    vmax = fmaxf(fmaxf(smax[0], smax[1]), fmaxf(smax[2], smax[3]));
    atomicMin(&ws[BMN + b * 16], map_ord(vmin));
    atomicMax(&ws[BMX + b * 16], map_ord(vmax));
  }
}

// K4: in-place per-batch min-max normalize (batch scale computed per-thread from hot lines)
__global__ __launch_bounds__(256) void k_norm(float* __restrict__ out,
                                              const uint32_t* __restrict__ ws) {
  const int idx = blockIdx.x * 256 + threadIdx.x;   // float4 index
  const int b = idx / CHW4;
  const float mn = unmap_ord(ws[BMN + b * 16]);
  const float mx = unmap_ord(ws[BMX + b * 16]);
  const float inv = 1.0f / fmaxf(mx - mn, 1e-8f);
  float4 v = ((float4*)out)[idx];
  v.x = (v.x - mn) * inv;
  v.y = (v.y - mn) * inv;
  v.z = (v.z - mn) * inv;
  v.w = (v.w - mn) * inv;
  ((float4*)out)[idx] = v;
}

extern "C" void kernel_launch(void* const* d_in, const int* in_sizes, int n_in,
                              void* d_out, int out_size, void* d_ws, size_t ws_size,
                              hipStream_t stream) {
  const float* img = (const float*)d_in[0];
  float* out = (float*)d_out;
  uint32_t* ws = (uint32_t*)d_ws;

  k_init<<<1, 256, 0, stream>>>(ws);
  k_bits<<<dim3(256, 3, 32), 256, 0, stream>>>((uint32_t*)out, ws);
  k_scales<<<1, 64, 0, stream>>>(ws);
  k_enc<<<dim3(256, 3, 32), 256, 0, stream>>>(img, out, ws);
  k_norm<<<24576, 256, 0, stream>>>(out, ws);
}